// Round 7
// baseline (401.686 us; speedup 1.0000x reference)
//
#include <hip/hip_runtime.h>

#define EPS 1e-6f
#define NCHUNK 32    // row chunks; rows/chunk = N/NCHUNK = 4096
#define WSLICE 16    // columns per slice
#define NSLICE 16    // D / WSLICE
#define LSTRIDE 17   // padded LDS row stride (floats) — randomizes banks

// ws layout (4-byte elems):
//   [0]      int   counts[C]
//   [C]      float loss_acc
//   [C+1]    float npres_acc
//   [C+2]    int   done
//   [C+3]    float partials[NCHUNK*NSLICE*C*WSLICE]   (~33 MB, fully overwritten)
// memset zeroes the first C+3 elems only.

__global__ void hist_kernel(const int* __restrict__ lbls,
                            int* __restrict__ counts, int n) {
    int i = blockIdx.x * blockDim.x + threadIdx.x;
    if (i < n) atomicAdd(&counts[lbls[i]], 1);
}

// 512 blocks = 32 chunks x 16 slices; each block streams its chunk's rows
// (contiguous, fully-coalesced 1 KB/wave-instr) and scatters into an
// LDS-privatized per-class partial sum for its 16-column slice.
__global__ __launch_bounds__(256)
void stream_kernel(const float* __restrict__ feats,
                   const int* __restrict__ lbls,
                   float* __restrict__ partials,
                   int n, int c, int d) {
    extern __shared__ float lsum[];   // c * LSTRIDE floats = 68 KB
    int bid = blockIdx.x;
    int s = bid & (NSLICE - 1);       // column slice
    int k = bid >> 4;                 // row chunk
    int t = threadIdx.x;

    int lds_elems = c * LSTRIDE;
    for (int i = t; i < lds_elems; i += 256) lsum[i] = 0.0f;
    __syncthreads();

    int rows = n / NCHUNK;            // 4096
    int row0 = k * rows;
    int rsub = t >> 2;                // 0..63: row offset within a 64-row tile
    int a    = t & 3;                 // which float4 of the 16-col slice

    const float4* f4 = (const float4*)feats;
    int stride4 = d >> 2;             // 64

    // 64 iterations of 64 rows; independent iterations -> compiler pipelines
#pragma unroll 4
    for (int it = 0; it < rows / 64; ++it) {
        int r = row0 + it * 64 + rsub;
        int lbl = lbls[r];
        float4 v = f4[(size_t)r * stride4 + s * 4 + a];
        float* base = &lsum[lbl * LSTRIDE + a * 4];
        unsafeAtomicAdd(base + 0, v.x);
        unsafeAtomicAdd(base + 1, v.y);
        unsafeAtomicAdd(base + 2, v.z);
        unsafeAtomicAdd(base + 3, v.w);
    }
    __syncthreads();

    // flush: partials[(k*NSLICE + s)*c*WSLICE + cc*WSLICE + col]
    float* dst = partials + (size_t)(k * NSLICE + s) * c * WSLICE;
    int tot = c * WSLICE;
    for (int i = t; i < tot; i += 256) {
        int cc = i >> 4, col = i & 15;
        dst[i] = lsum[cc * LSTRIDE + col];
    }
}

// one block per class: reduce NCHUNK partials per column, mean + Mahalanobis,
// block reduce, last-done block computes the final scalar.
__global__ __launch_bounds__(256)
void finalize_kernel(const float* __restrict__ partials,
                     const int* __restrict__ counts,
                     const float* __restrict__ proto,
                     const float* __restrict__ cov,
                     float* __restrict__ loss_acc,
                     float* __restrict__ npres_acc,
                     int* __restrict__ done,
                     float* __restrict__ out, int c_total, int d) {
    int c = blockIdx.x;
    int t = threadIdx.x;               // global col = (t>>4)*16 + (t&15) == t
    int s = t >> 4, col = t & 15;

    float a = 0.0f;
    for (int k = 0; k < NCHUNK; ++k)
        a += partials[(size_t)(k * NSLICE + s) * c_total * WSLICE
                      + (size_t)c * WSLICE + col];

    int cnt = counts[c];
    float present = (cnt > 0) ? 1.0f : 0.0f;
    float mean = a / fmaxf((float)cnt, 1.0f);
    size_t idx = (size_t)c * d + t;
    float diff = mean - proto[idx];
    float pe = present * diff * diff / (cov[idx] + EPS);

    for (int off = 32; off > 0; off >>= 1)
        pe += __shfl_down(pe, off, 64);
    __shared__ float sred[4];
    if ((t & 63) == 0) sred[t >> 6] = pe;
    __syncthreads();
    if (t == 0) {
        atomicAdd(loss_acc, (sred[0] + sred[1]) + (sred[2] + sred[3]));
        atomicAdd(npres_acc, present);
        __threadfence();
        int prev = atomicAdd(done, 1);
        if (prev == c_total - 1) {
            float L = atomicAdd(loss_acc, 0.0f);   // coherent read
            float P = atomicAdd(npres_acc, 0.0f);
            out[0] = L / (P * (float)d);
        }
    }
}

extern "C" void kernel_launch(void* const* d_in, const int* in_sizes, int n_in,
                              void* d_out, int out_size, void* d_ws, size_t ws_size,
                              hipStream_t stream) {
    const float* feats = (const float*)d_in[0];
    const int*   lbls  = (const int*)d_in[1];
    const float* proto = (const float*)d_in[2];
    const float* cov   = (const float*)d_in[3];

    int n_rows = in_sizes[1];              // N = 131072
    int d      = in_sizes[0] / n_rows;     // D = 256
    int c      = in_sizes[2] / d;          // C = 1000

    int*   counts    = (int*)d_ws;
    float* loss_acc  = (float*)d_ws + c;
    float* npres_acc = loss_acc + 1;
    int*   done      = (int*)d_ws + c + 2;
    float* partials  = (float*)d_ws + c + 3;

    hipMemsetAsync(d_ws, 0, ((size_t)c + 3) * sizeof(int), stream);

    int nb = (n_rows + 255) / 256;
    hist_kernel<<<nb, 256, 0, stream>>>(lbls, counts, n_rows);

    size_t lds_bytes = (size_t)c * LSTRIDE * sizeof(float);   // 68 KB
    stream_kernel<<<NCHUNK * NSLICE, 256, lds_bytes, stream>>>(
        feats, lbls, partials, n_rows, c, d);

    finalize_kernel<<<c, 256, 0, stream>>>(partials, counts, proto, cov,
                                           loss_acc, npres_acc, done,
                                           (float*)d_out, c, d);
}